// Round 4
// baseline (5452.130 us; speedup 1.0000x reference)
//
#include <hip/hip_runtime.h>
#include <stdint.h>

// B=1024, N=16, D=64, H=64, A=64 -> 16384 nodes. All tensors fp32.
#define NNODE 16384
#define TAU_ 0.01f
#define EPSG 1e-10f

// ---- workspace layout (float offsets); total 1,114,112 floats = 4.25 MB ----
#define OFF_WENC 0
#define OFF_BENC 4096
#define OFF_WIHF 4160
#define OFF_WHHF 28736
#define OFF_BIHF 41024
#define OFF_BHHF 41216
#define OFF_WIHB 41408
#define OFF_WHHB 65984
#define OFF_BIHB 78272
#define OFF_BHHB 78464
#define OFF_WHARD 78656
#define OFF_BHARD 78912
#define OFF_WQ 78914
#define OFF_WK 83010
#define OFF_WV 87106
#define OFF_BV 91202
#define OFF_WIHC 91266
#define OFF_WHHC 103554
#define OFF_BIHC 115842
#define OFF_BHHC 116034
#define OFF_YF 131072
#define OFF_YB (OFF_YF + 491520)
#define WS_FLOATS (OFF_YB + 491520)

__device__ __forceinline__ float sigf(float x){ return 1.0f/(1.0f + __expf(-x)); }
__device__ __forceinline__ float tanhfast(float x){ return 1.0f - 2.0f/(__expf(2.0f*x)+1.0f); }

// ---------------- K0: copy all weights into contiguous ws ----------------
struct Prep {
  const float* s[20];
  int n[20];
  int o[20];
};
__global__ void k_prep(Prep p, float* __restrict__ ws){
  int a = blockIdx.y;
  int i = blockIdx.x * blockDim.x + threadIdx.x;
  if (i < p.n[a]) ws[p.o[a] + i] = p.s[a][i];
}

// ---------------- K1: bidirectional 15-step GRU; grid 512 (dir = bid>>8) ----
// 512 thr = 8 grps x 8 l-values. No large register arrays: h streamed from LDS.
// LDS 69 KB -> 2 blocks/CU (16 waves). Loop live-set ~80 VGPR -> no spills.
__global__ __launch_bounds__(512, 4) void k_gru(const float* __restrict__ obs,
                                                float* __restrict__ ws){
  __shared__ float s_u[192*64];   // 48 KB   u[g][local node]
  __shared__ float s_h[64*68];    // 17.4 KB obs tile -> h_enc -> GRU state [node][d]
  __shared__ float s_ap[1024];    // 4 KB    logit partials (2 x 8 grp x 64 node)
  const int tid = threadIdx.x;
  const int nl  = tid & 63;
  const int grp = __builtin_amdgcn_readfirstlane(tid >> 6);
  const int dir = blockIdx.x >> 8;
  const int base = (blockIdx.x & 255) * 64;

  // P0: stage obs tile [node][68]
  for (int k = tid; k < 4096; k += 512)
    s_h[(k>>6)*68 + (k&63)] = obs[base*64 + k];
  __syncthreads();

  // P1: h_enc for own 8 l's (streaming obs from LDS)
  const float* wenc = ws + OFF_WENC;
  const float* benc = ws + OFF_BENC;
  float he[8];
  #pragma unroll
  for (int il = 0; il < 8; il++) he[il] = benc[grp*8 + il];
  #pragma unroll
  for (int dq = 0; dq < 16; dq++){
    float4 o4 = *(const float4*)&s_h[nl*68 + 4*dq];
    #pragma unroll
    for (int il = 0; il < 8; il++){
      int l = grp*8 + il;
      he[il] += o4.x*wenc[(4*dq+0)*64+l] + o4.y*wenc[(4*dq+1)*64+l]
              + o4.z*wenc[(4*dq+2)*64+l] + o4.w*wenc[(4*dq+3)*64+l];
    }
  }
  __syncthreads();
  #pragma unroll
  for (int il = 0; il < 8; il++) s_h[nl*68 + grp*8 + il] = fmaxf(he[il], 0.0f);
  __syncthreads();

  // P2: cb (h_i input contribution, bhh_r/z folded) + u (h_j contribution)
  const float* wih = ws + (dir ? OFF_WIHB : OFF_WIHF);
  const float* bih = ws + (dir ? OFF_BIHB : OFF_BIHF);
  const float* bhh = ws + (dir ? OFF_BHHB : OFF_BHHF);
  float cb[24], ua[24], bhn[8];
  #pragma unroll
  for (int il = 0; il < 8; il++){
    int l = grp*8 + il;
    cb[il*3+0] = bih[l]      + bhh[l];
    cb[il*3+1] = bih[64+l]   + bhh[64+l];
    cb[il*3+2] = bih[128+l];                // bhh_n NOT foldable (scaled by r)
    bhn[il]    = bhh[128+l];
    ua[il*3+0] = 0.f; ua[il*3+1] = 0.f; ua[il*3+2] = 0.f;
  }
  #pragma unroll
  for (int dq = 0; dq < 16; dq++){
    float4 h4 = *(const float4*)&s_h[nl*68 + 4*dq];
    #pragma unroll
    for (int il = 0; il < 8; il++){
      #pragma unroll
      for (int g = 0; g < 3; g++){
        const float* wr = wih + (g*64 + grp*8 + il)*128 + 4*dq;
        cb[il*3+g] += h4.x*wr[0]  + h4.y*wr[1]  + h4.z*wr[2]  + h4.w*wr[3];
        ua[il*3+g] += h4.x*wr[64] + h4.y*wr[65] + h4.z*wr[66] + h4.w*wr[67];
      }
    }
  }
  #pragma unroll
  for (int il = 0; il < 8; il++){
    #pragma unroll
    for (int g = 0; g < 3; g++)
      s_u[(g*64 + grp*8 + il)*64 + nl] = ua[il*3+g];
  }
  __syncthreads();                       // also covers: all P2 s_h reads done
  for (int k = tid; k < 64*68; k += 512) s_h[k] = 0.0f;
  __syncthreads();

  // P3: 15-step recurrence
  const float* whh   = ws + (dir ? OFF_WHHB : OFF_WHHF);
  const float* whard = ws + OFF_WHARD + dir*128;   // rows l (fwd) / 64+l (bwd)
  float* yout        = ws + (dir ? OFF_YB : OFF_YF);
  const int i_b   = nl & 15;
  const int jbase = nl & 48;

  for (int kk = 0; kk < 15; kk++){
    const int t  = dir ? (14 - kk) : kk;
    const int jl = jbase | (t + (t >= i_b ? 1 : 0));
    float acc[24];
    #pragma unroll
    for (int q = 0; q < 24; q++) acc[q] = 0.f;
    #pragma unroll
    for (int dq = 0; dq < 16; dq++){
      float4 h4 = *(const float4*)&s_h[nl*68 + 4*dq];
      #pragma unroll
      for (int il = 0; il < 8; il++){
        #pragma unroll
        for (int g = 0; g < 3; g++){
          const float* wr = whh + (g*64 + grp*8 + il)*64 + 4*dq;
          acc[il*3+g] += h4.x*wr[0] + h4.y*wr[1] + h4.z*wr[2] + h4.w*wr[3];
        }
      }
    }
    float hold[8], hv[8];
    #pragma unroll
    for (int il = 0; il < 8; il++) hold[il] = s_h[nl*68 + grp*8 + il];
    float pa0 = 0.f, pa1 = 0.f;
    #pragma unroll
    for (int il = 0; il < 8; il++){
      int l = grp*8 + il;
      float r = sigf(cb[il*3+0] + s_u[(l     )*64 + jl] + acc[il*3+0]);
      float z = sigf(cb[il*3+1] + s_u[(64 + l)*64 + jl] + acc[il*3+1]);
      float n = tanhfast(cb[il*3+2] + s_u[(128+l)*64 + jl] + r*(bhn[il] + acc[il*3+2]));
      float hnew = (1.0f - z)*n + z*hold[il];
      hv[il] = hnew;
      pa0 += hnew * whard[l*2 + 0];
      pa1 += hnew * whard[l*2 + 1];
    }
    __syncthreads();                      // all s_h reads of this step done
    #pragma unroll
    for (int il = 0; il < 8; il++) s_h[nl*68 + grp*8 + il] = hv[il];
    s_ap[       grp*64 + nl] = pa0;
    s_ap[512 +  grp*64 + nl] = pa1;
    __syncthreads();
    if (tid < 64){
      float a0 = 0.f, a1 = 0.f;
      #pragma unroll
      for (int g = 0; g < 8; g++){ a0 += s_ap[g*64 + nl]; a1 += s_ap[512 + g*64 + nl]; }
      *(float2*)&yout[((base + nl)*15 + t)*2] = make_float2(a0, a1);
    }
  }
}

// ---------------- K2: qkv + gumbel + attention + final GRU cell -------------
// 256 thr = 4 grps x 16. All big arrays streamed via LDS; live-set ~65 VGPR.
__global__ __launch_bounds__(256, 2) void k_attn(const float* __restrict__ obs,
                                                 const float* __restrict__ hid,
                                                 const float* __restrict__ gum,
                                                 float* __restrict__ ws,
                                                 float* __restrict__ out){
  __shared__ float smem[16384];          // 64 KB -> 2 blocks/CU
  float* s_k  = smem;                    // 4096  [a][node]
  float* s_v  = smem + 4096;             // 4096
  float* s_x  = smem + 8192;             // 4352  [node][68]: obs -> h_enc -> x
  float* s_sp = smem + 12544;            // 3840  score partials
  float* s_h0 = smem;                    // 4352, aliases dead s_k/s_v (late phases)
  const int tid = threadIdx.x;
  const int nl  = tid & 63;
  const int grp = __builtin_amdgcn_readfirstlane(tid >> 6);
  const int base = blockIdx.x * 64;
  const int node = base + nl;

  // P0: stage obs
  for (int k = tid; k < 4096; k += 256)
    s_x[(k>>6)*68 + (k&63)] = obs[base*64 + k];
  __syncthreads();

  // P1: h_enc own 16 l's
  const float* wenc = ws + OFF_WENC; const float* benc = ws + OFF_BENC;
  float he[16];
  #pragma unroll
  for (int il = 0; il < 16; il++) he[il] = benc[grp*16 + il];
  #pragma unroll
  for (int dq = 0; dq < 16; dq++){
    float4 o4 = *(const float4*)&s_x[nl*68 + 4*dq];
    #pragma unroll
    for (int il = 0; il < 16; il++){
      int l = grp*16 + il;
      he[il] += o4.x*wenc[(4*dq+0)*64+l] + o4.y*wenc[(4*dq+1)*64+l]
              + o4.z*wenc[(4*dq+2)*64+l] + o4.w*wenc[(4*dq+3)*64+l];
    }
  }
  __syncthreads();
  #pragma unroll
  for (int il = 0; il < 16; il++) s_x[nl*68 + grp*16 + il] = fmaxf(he[il], 0.0f);
  __syncthreads();

  // P2: q,k,v (stream h from s_x)
  const float* wq = ws+OFF_WQ; const float* wk = ws+OFF_WK;
  const float* wv = ws+OFF_WV; const float* bv = ws+OFF_BV;
  float aq[16], ak[16], av[16];
  #pragma unroll
  for (int il = 0; il < 16; il++){ aq[il]=0.f; ak[il]=0.f; av[il]=bv[grp*16+il]; }
  #pragma unroll
  for (int dq = 0; dq < 16; dq++){
    float4 h4 = *(const float4*)&s_x[nl*68 + 4*dq];
    #pragma unroll
    for (int il = 0; il < 16; il++){
      int a = grp*16 + il;
      aq[il] += h4.x*wq[(4*dq+0)*64+a] + h4.y*wq[(4*dq+1)*64+a]
              + h4.z*wq[(4*dq+2)*64+a] + h4.w*wq[(4*dq+3)*64+a];
      ak[il] += h4.x*wk[(4*dq+0)*64+a] + h4.y*wk[(4*dq+1)*64+a]
              + h4.z*wk[(4*dq+2)*64+a] + h4.w*wk[(4*dq+3)*64+a];
      av[il] += h4.x*wv[(4*dq+0)*64+a] + h4.y*wv[(4*dq+1)*64+a]
              + h4.z*wv[(4*dq+2)*64+a] + h4.w*wv[(4*dq+3)*64+a];
    }
  }
  #pragma unroll
  for (int il = 0; il < 16; il++){
    int a = grp*16 + il;
    s_k[a*64 + nl] = ak[il];
    s_v[a*64 + nl] = fmaxf(av[il], 0.f);
  }
  __syncthreads();

  // P3: scores (partial over this grp's 16 a-dims)
  const int i_b = nl & 15, jbase = nl & 48;
  #pragma unroll
  for (int t = 0; t < 15; t++){
    int jl = jbase | (t + (t >= i_b ? 1 : 0));
    float s = 0.f;
    #pragma unroll
    for (int il = 0; il < 16; il++) s += aq[il]*s_k[(grp*16+il)*64 + jl];
    s_sp[t*256 + grp*64 + nl] = s;
  }
  __syncthreads();

  // P4: softmax + gumbel-hard coefficient
  float sc[15], e[15];
  float m = -1e30f;
  #pragma unroll
  for (int t = 0; t < 15; t++){
    float s = (s_sp[t*256+nl] + s_sp[t*256+64+nl] +
               s_sp[t*256+128+nl] + s_sp[t*256+192+nl]) * 0.125f;
    sc[t] = s; m = fmaxf(m, s);
  }
  float den = 0.f;
  #pragma unroll
  for (int t = 0; t < 15; t++){ e[t] = __expf(sc[t]-m); den += e[t]; }
  float rden = 1.0f/den;

  const float bh0 = ws[OFF_BHARD], bh1 = ws[OFF_BHARD+1];
  const float* yF = ws + OFF_YF; const float* yB = ws + OFF_YB;
  float coeff[15];
  #pragma unroll
  for (int t = 0; t < 15; t++){
    int rowb = (node*15 + t)*2;
    float y0 = yF[rowb]   + yB[rowb]   + bh0;
    float y1 = yF[rowb+1] + yB[rowb+1] + bh1;
    float2 u2 = *(const float2*)&gum[rowb];
    float g0 = -__logf(-__logf(u2.x + EPSG) + EPSG);
    float g1 = -__logf(-__logf(u2.y + EPSG) + EPSG);
    float w  = sigf(((y1+g1) - (y0+g0)) * (1.0f/TAU_));
    coeff[t] = e[t]*rden*w;
  }

  // P5: x accumulation; overwrite s_x (h dead since P3-barrier)
  float xa[16];
  #pragma unroll
  for (int il = 0; il < 16; il++) xa[il] = 0.f;
  #pragma unroll
  for (int t = 0; t < 15; t++){
    int jl = jbase | (t + (t >= i_b ? 1 : 0));
    float c = coeff[t];
    #pragma unroll
    for (int il = 0; il < 16; il++) xa[il] += c*s_v[(grp*16+il)*64 + jl];
  }
  #pragma unroll
  for (int il = 0; il < 16; il++) s_x[nl*68 + grp*16 + il] = xa[il];
  __syncthreads();

  // P6: stage hidden_state into s_h0 (aliases dead s_k/s_v)
  for (int k = tid; k < 4096; k += 256)
    s_h0[(k>>6)*68 + (k&63)] = hid[base*64 + k];
  __syncthreads();

  // P7: final GRU cell, il-blocked by 4, streaming x/h0 from LDS
  const float* wih = ws+OFF_WIHC; const float* whc = ws+OFF_WHHC;
  const float* bih = ws+OFF_BIHC; const float* bhc = ws+OFF_BHHC;
  for (int ilb = 0; ilb < 4; ilb++){
    float ac[24];
    #pragma unroll
    for (int q = 0; q < 4; q++){
      int l = grp*16 + ilb*4 + q;
      ac[q*6+0] = bih[l]; ac[q*6+1] = bih[64+l]; ac[q*6+2] = bih[128+l];
      ac[q*6+3] = bhc[l]; ac[q*6+4] = bhc[64+l]; ac[q*6+5] = bhc[128+l];
    }
    #pragma unroll
    for (int dq = 0; dq < 16; dq++){
      float4 x4 = *(const float4*)&s_x [nl*68 + 4*dq];
      float4 h4 = *(const float4*)&s_h0[nl*68 + 4*dq];
      #pragma unroll
      for (int q = 0; q < 4; q++){
        int l = grp*16 + ilb*4 + q;
        const float* w0 = wih + (l     )*64 + 4*dq;
        const float* w1 = wih + (64 + l)*64 + 4*dq;
        const float* w2 = wih + (128+ l)*64 + 4*dq;
        const float* m0 = whc + (l     )*64 + 4*dq;
        const float* m1 = whc + (64 + l)*64 + 4*dq;
        const float* m2 = whc + (128+ l)*64 + 4*dq;
        ac[q*6+0] += x4.x*w0[0]+x4.y*w0[1]+x4.z*w0[2]+x4.w*w0[3];
        ac[q*6+1] += x4.x*w1[0]+x4.y*w1[1]+x4.z*w1[2]+x4.w*w1[3];
        ac[q*6+2] += x4.x*w2[0]+x4.y*w2[1]+x4.z*w2[2]+x4.w*w2[3];
        ac[q*6+3] += h4.x*m0[0]+h4.y*m0[1]+h4.z*m0[2]+h4.w*m0[3];
        ac[q*6+4] += h4.x*m1[0]+h4.y*m1[1]+h4.z*m1[2]+h4.w*m1[3];
        ac[q*6+5] += h4.x*m2[0]+h4.y*m2[1]+h4.z*m2[2]+h4.w*m2[3];
      }
    }
    #pragma unroll
    for (int q = 0; q < 4; q++){
      int l = grp*16 + ilb*4 + q;
      float r = sigf(ac[q*6+0] + ac[q*6+3]);
      float z = sigf(ac[q*6+1] + ac[q*6+4]);
      float n = tanhfast(ac[q*6+2] + r*ac[q*6+5]);
      out[node*64 + l] = (1.0f - z)*n + z*s_h0[nl*68 + l];
    }
  }
}

extern "C" void kernel_launch(void* const* d_in, const int* in_sizes, int n_in,
                              void* d_out, int out_size, void* d_ws, size_t ws_size,
                              hipStream_t stream){
  if (ws_size < (size_t)WS_FLOATS * sizeof(float)) return;
  float* ws = (float*)d_ws;
  static const int offs[20] = {OFF_WENC, OFF_BENC, OFF_WIHF, OFF_WHHF, OFF_BIHF, OFF_BHHF,
      OFF_WIHB, OFF_WHHB, OFF_BIHB, OFF_BHHB, OFF_WHARD, OFF_BHARD, OFF_WQ, OFF_WK, OFF_WV,
      OFF_BV, OFF_WIHC, OFF_WHHC, OFF_BIHC, OFF_BHHC};
  Prep p;
  for (int i = 0; i < 20; i++){
    p.s[i] = (const float*)d_in[3 + i];
    p.n[i] = in_sizes[3 + i];
    p.o[i] = offs[i];
  }
  hipLaunchKernelGGL(k_prep, dim3(96, 20), dim3(256), 0, stream, p, ws);
  hipLaunchKernelGGL(k_gru,  dim3(512),    dim3(512), 0, stream,
                     (const float*)d_in[0], ws);
  hipLaunchKernelGGL(k_attn, dim3(256),    dim3(256), 0, stream,
                     (const float*)d_in[0], (const float*)d_in[1],
                     (const float*)d_in[2], ws, (float*)d_out);
}

// Round 7
// 1203.503 us; speedup vs baseline: 4.5302x; 4.5302x over previous
//
#include <hip/hip_runtime.h>
#include <stdint.h>

// B=1024, N=16, D=64, H=64, A=64 -> 16384 nodes. All tensors fp32.
#define NNODE 16384
#define TAU_ 0.01f
#define EPSG 1e-10f

// ---- workspace layout (float offsets); total 1,114,112 floats = 4.25 MB ----
#define OFF_WENC 0
#define OFF_BENC 4096
#define OFF_WIHF 4160
#define OFF_WHHF 28736
#define OFF_BIHF 41024
#define OFF_BHHF 41216
#define OFF_WIHB 41408
#define OFF_WHHB 65984
#define OFF_BIHB 78272
#define OFF_BHHB 78464
#define OFF_WHARD 78656
#define OFF_BHARD 78912
#define OFF_WQ 78914
#define OFF_WK 83010
#define OFF_WV 87106
#define OFF_BV 91202
#define OFF_WIHC 91266
#define OFF_WHHC 103554
#define OFF_BIHC 115842
#define OFF_BHHC 116034
#define OFF_YF 131072
#define OFF_YB (OFF_YF + 491520)
#define WS_FLOATS (OFF_YB + 491520)

__device__ __forceinline__ float sigf(float x){ return 1.0f/(1.0f + __expf(-x)); }
__device__ __forceinline__ float tanhfast(float x){ return 1.0f - 2.0f/(__expf(2.0f*x)+1.0f); }

// ---------------- K0: copy all weights into contiguous ws ----------------
struct Prep {
  const float* s[20];
  int n[20];
  int o[20];
};
__global__ void k_prep(Prep p, float* __restrict__ ws){
  int a = blockIdx.y;
  int i = blockIdx.x * blockDim.x + threadIdx.x;
  if (i < p.n[a]) ws[p.o[a] + i] = p.s[a][i];
}

// ---------------- K1: bidirectional 15-step GRU; grid 512 (dir = bid>>8) ----
// 512 thr = 8 grps x 8 l-values. Hot-loop live-set ~55 VGPR: cb in LDS
// (odd-quad stride 196 -> conflict-free b128), hold carried in hv[] regs.
// LDS 118 KB -> 1 block/CU by design; (512,1) leaves the allocator free.
__global__ __launch_bounds__(512, 1) void k_gru(const float* __restrict__ obs,
                                                float* __restrict__ ws){
  __shared__ float smem[30208];          // 118 KB
  float* s_u  = smem;                    // 192*64 = 12288   u[g][node]
  float* s_cb = smem + 12288;            // 64*196 = 12544   cb[node][grp*24+...]
  float* s_h  = smem + 24832;            // 64*68  = 4352    obs -> h_enc -> state
  float* s_ap = smem + 29184;            // 1024             logit partials
  const int tid = threadIdx.x;
  const int nl  = tid & 63;
  const int grp = __builtin_amdgcn_readfirstlane(tid >> 6);
  const int dir = blockIdx.x >> 8;
  const int base = (blockIdx.x & 255) * 64;

  // P0: stage obs tile [node][68]
  for (int k = tid; k < 4096; k += 512)
    s_h[(k>>6)*68 + (k&63)] = obs[base*64 + k];
  __syncthreads();

  // P1: h_enc for own 8 l's
  const float* wenc = ws + OFF_WENC;
  const float* benc = ws + OFF_BENC;
  {
    float he[8];
    #pragma unroll
    for (int il = 0; il < 8; il++) he[il] = benc[grp*8 + il];
    #pragma unroll
    for (int dq = 0; dq < 16; dq++){
      float4 o4 = *(const float4*)&s_h[nl*68 + 4*dq];
      #pragma unroll
      for (int il = 0; il < 8; il++){
        int l = grp*8 + il;
        he[il] += o4.x*wenc[(4*dq+0)*64+l] + o4.y*wenc[(4*dq+1)*64+l]
                + o4.z*wenc[(4*dq+2)*64+l] + o4.w*wenc[(4*dq+3)*64+l];
      }
    }
    __syncthreads();
    #pragma unroll
    for (int il = 0; il < 8; il++) s_h[nl*68 + grp*8 + il] = fmaxf(he[il], 0.0f);
  }
  __syncthreads();

  const float* wih = ws + (dir ? OFF_WIHB : OFF_WIHF);
  const float* bih = ws + (dir ? OFF_BIHB : OFF_BIHF);
  const float* bhh = ws + (dir ? OFF_BHHB : OFF_BHHF);

  // P2a: u[g][node] -> s_u   (live ~35)
  {
    float ua[24];
    #pragma unroll
    for (int c = 0; c < 24; c++) ua[c] = 0.f;
    #pragma unroll
    for (int dq = 0; dq < 16; dq++){
      float4 h4 = *(const float4*)&s_h[nl*68 + 4*dq];
      #pragma unroll
      for (int c = 0; c < 24; c++){
        const float* wr = wih + ((c>>3)*64 + grp*8 + (c&7))*128 + 64 + 4*dq;
        ua[c] += h4.x*wr[0] + h4.y*wr[1] + h4.z*wr[2] + h4.w*wr[3];
      }
    }
    #pragma unroll
    for (int c = 0; c < 24; c++)
      s_u[((c>>3)*64 + grp*8 + (c&7))*64 + nl] = ua[c];
  }

  // P2b: cb -> s_cb.  [0..7]=r (bih+bhh folded), [8..15]=z (folded),
  //      [16..23]=n (bih_n + Wih_n.h_i ONLY -- bhh_n/Whh_n stay inside r).
  float bhn[8];
  #pragma unroll
  for (int il = 0; il < 8; il++) bhn[il] = bhh[128 + grp*8 + il];
  {
    float cbl[24];
    #pragma unroll
    for (int c = 0; c < 24; c++){
      int g = c>>3, l = grp*8 + (c&7);
      cbl[c] = bih[g*64 + l] + (g < 2 ? bhh[g*64 + l] : 0.0f);
    }
    #pragma unroll
    for (int dq = 0; dq < 16; dq++){
      float4 h4 = *(const float4*)&s_h[nl*68 + 4*dq];
      #pragma unroll
      for (int c = 0; c < 24; c++){
        const float* wr = wih + ((c>>3)*64 + grp*8 + (c&7))*128 + 4*dq;
        cbl[c] += h4.x*wr[0] + h4.y*wr[1] + h4.z*wr[2] + h4.w*wr[3];
      }
    }
    #pragma unroll
    for (int m = 0; m < 6; m++)
      *(float4*)&s_cb[nl*196 + grp*24 + 4*m] =
        make_float4(cbl[4*m], cbl[4*m+1], cbl[4*m+2], cbl[4*m+3]);
  }
  __syncthreads();                        // all P2 s_h reads done
  for (int k = tid; k < 64*68; k += 512) s_h[k] = 0.0f;
  __syncthreads();

  // P3: 15-step recurrence
  const float* whh   = ws + (dir ? OFF_WHHB : OFF_WHHF);
  const float* whard = ws + OFF_WHARD + dir*128;    // rows l (fwd) / 64+l (bwd)
  float* yout        = ws + (dir ? OFF_YB : OFF_YF);
  const int i_b   = nl & 15;
  const int jbase = nl & 48;

  float hv[8];
  #pragma unroll
  for (int il = 0; il < 8; il++) hv[il] = 0.0f;

  for (int kk = 0; kk < 15; kk++){
    const int t  = dir ? (14 - kk) : kk;
    const int jl = jbase | (t + (t >= i_b ? 1 : 0));
    // acc init: r/z from cb; n-gate accumulates PURE Whh_n.h (starts at 0)
    float acc[24];
    #pragma unroll
    for (int m = 0; m < 4; m++){
      float4 c4 = *(const float4*)&s_cb[nl*196 + grp*24 + 4*m];
      acc[4*m]=c4.x; acc[4*m+1]=c4.y; acc[4*m+2]=c4.z; acc[4*m+3]=c4.w;
    }
    #pragma unroll
    for (int c = 16; c < 24; c++) acc[c] = 0.f;
    // += Whh . h   (h streamed from LDS, weights wave-uniform)
    #pragma unroll
    for (int dq = 0; dq < 16; dq++){
      float4 h4 = *(const float4*)&s_h[nl*68 + 4*dq];
      #pragma unroll
      for (int c = 0; c < 24; c++){
        const float* wr = whh + ((c>>3)*64 + grp*8 + (c&7))*64 + 4*dq;
        acc[c] += h4.x*wr[0] + h4.y*wr[1] + h4.z*wr[2] + h4.w*wr[3];
      }
    }
    float pa0 = 0.f, pa1 = 0.f;
    #pragma unroll
    for (int il = 0; il < 8; il++){
      int l = grp*8 + il;
      float cbn = s_cb[nl*196 + grp*24 + 16 + il];
      float r = sigf(acc[il]      + s_u[(l      )*64 + jl]);
      float z = sigf(acc[8 + il]  + s_u[(64 + l )*64 + jl]);
      float n = tanhfast(cbn + s_u[(128+l)*64 + jl] + r*(bhn[il] + acc[16+il]));
      float hnew = (1.0f - z)*n + z*hv[il];
      hv[il] = hnew;
      pa0 += hnew * whard[l*2 + 0];
      pa1 += hnew * whard[l*2 + 1];
    }
    __syncthreads();                      // all s_h reads of this step done
    *(float4*)&s_h[nl*68 + grp*8    ] = make_float4(hv[0],hv[1],hv[2],hv[3]);
    *(float4*)&s_h[nl*68 + grp*8 + 4] = make_float4(hv[4],hv[5],hv[6],hv[7]);
    s_ap[       grp*64 + nl] = pa0;
    s_ap[512 +  grp*64 + nl] = pa1;
    __syncthreads();
    if (tid < 64){
      float a0 = 0.f, a1 = 0.f;
      #pragma unroll
      for (int g = 0; g < 8; g++){ a0 += s_ap[g*64 + nl]; a1 += s_ap[512 + g*64 + nl]; }
      *(float2*)&yout[((base + nl)*15 + t)*2] = make_float2(a0, a1);
    }
  }
}

// ---------------- K2: qkv + gumbel + attention + final GRU cell -------------
// 256 thr = 4 grps x 16. Sequential low-live passes; peak live ~50 VGPR.
__global__ __launch_bounds__(256, 1) void k_attn(const float* __restrict__ obs,
                                                 const float* __restrict__ hid,
                                                 const float* __restrict__ gum,
                                                 float* __restrict__ ws,
                                                 float* __restrict__ out){
  __shared__ float smem[16384];          // 64 KB
  float* s_k  = smem;                    // 4096  [a][node]
  float* s_v  = smem + 4096;             // 4096
  float* s_x  = smem + 8192;             // 4352  [node][68]: obs -> h_enc -> x
  float* s_sp = smem + 12544;            // 3840  score partials
  float* s_h0 = smem;                    // 4352, aliases dead s_k/s_v (late phases)
  const int tid = threadIdx.x;
  const int nl  = tid & 63;
  const int grp = __builtin_amdgcn_readfirstlane(tid >> 6);
  const int base = blockIdx.x * 64;
  const int node = base + nl;

  // P0: stage obs
  for (int k = tid; k < 4096; k += 256)
    s_x[(k>>6)*68 + (k&63)] = obs[base*64 + k];
  __syncthreads();

  // P1: h_enc own 16 l's
  const float* wenc = ws + OFF_WENC; const float* benc = ws + OFF_BENC;
  {
    float he[16];
    #pragma unroll
    for (int il = 0; il < 16; il++) he[il] = benc[grp*16 + il];
    #pragma unroll
    for (int dq = 0; dq < 16; dq++){
      float4 o4 = *(const float4*)&s_x[nl*68 + 4*dq];
      #pragma unroll
      for (int il = 0; il < 16; il++){
        int l = grp*16 + il;
        he[il] += o4.x*wenc[(4*dq+0)*64+l] + o4.y*wenc[(4*dq+1)*64+l]
                + o4.z*wenc[(4*dq+2)*64+l] + o4.w*wenc[(4*dq+3)*64+l];
      }
    }
    __syncthreads();
    #pragma unroll
    for (int il = 0; il < 16; il++) s_x[nl*68 + grp*16 + il] = fmaxf(he[il], 0.0f);
  }
  __syncthreads();

  // P2: k, v, q in three sequential passes (peak live ~25)
  const float* wq = ws+OFF_WQ; const float* wk = ws+OFF_WK;
  const float* wv = ws+OFF_WV; const float* bv = ws+OFF_BV;
  {
    float ak[16];
    #pragma unroll
    for (int il = 0; il < 16; il++) ak[il] = 0.f;
    #pragma unroll
    for (int dq = 0; dq < 16; dq++){
      float4 h4 = *(const float4*)&s_x[nl*68 + 4*dq];
      #pragma unroll
      for (int il = 0; il < 16; il++){
        int a = grp*16 + il;
        ak[il] += h4.x*wk[(4*dq+0)*64+a] + h4.y*wk[(4*dq+1)*64+a]
                + h4.z*wk[(4*dq+2)*64+a] + h4.w*wk[(4*dq+3)*64+a];
      }
    }
    #pragma unroll
    for (int il = 0; il < 16; il++) s_k[(grp*16+il)*64 + nl] = ak[il];
  }
  {
    float av[16];
    #pragma unroll
    for (int il = 0; il < 16; il++) av[il] = bv[grp*16+il];
    #pragma unroll
    for (int dq = 0; dq < 16; dq++){
      float4 h4 = *(const float4*)&s_x[nl*68 + 4*dq];
      #pragma unroll
      for (int il = 0; il < 16; il++){
        int a = grp*16 + il;
        av[il] += h4.x*wv[(4*dq+0)*64+a] + h4.y*wv[(4*dq+1)*64+a]
                + h4.z*wv[(4*dq+2)*64+a] + h4.w*wv[(4*dq+3)*64+a];
      }
    }
    #pragma unroll
    for (int il = 0; il < 16; il++) s_v[(grp*16+il)*64 + nl] = fmaxf(av[il], 0.f);
  }
  float aq[16];
  #pragma unroll
  for (int il = 0; il < 16; il++) aq[il] = 0.f;
  #pragma unroll
  for (int dq = 0; dq < 16; dq++){
    float4 h4 = *(const float4*)&s_x[nl*68 + 4*dq];
    #pragma unroll
    for (int il = 0; il < 16; il++){
      int a = grp*16 + il;
      aq[il] += h4.x*wq[(4*dq+0)*64+a] + h4.y*wq[(4*dq+1)*64+a]
              + h4.z*wq[(4*dq+2)*64+a] + h4.w*wq[(4*dq+3)*64+a];
    }
  }
  __syncthreads();

  // P3: scores (partial over this grp's 16 a-dims)
  const int i_b = nl & 15, jbase = nl & 48;
  #pragma unroll
  for (int t = 0; t < 15; t++){
    int jl = jbase | (t + (t >= i_b ? 1 : 0));
    float s = 0.f;
    #pragma unroll
    for (int il = 0; il < 16; il++) s += aq[il]*s_k[(grp*16+il)*64 + jl];
    s_sp[t*256 + grp*64 + nl] = s;
  }
  __syncthreads();

  // P4: softmax + gumbel-hard coefficient
  float coeff[15];
  {
    float sc[15];
    float m = -1e30f;
    #pragma unroll
    for (int t = 0; t < 15; t++){
      float s = (s_sp[t*256+nl] + s_sp[t*256+64+nl] +
                 s_sp[t*256+128+nl] + s_sp[t*256+192+nl]) * 0.125f;
      sc[t] = s; m = fmaxf(m, s);
    }
    float den = 0.f;
    #pragma unroll
    for (int t = 0; t < 15; t++){ sc[t] = __expf(sc[t]-m); den += sc[t]; }
    float rden = 1.0f/den;
    const float bh0 = ws[OFF_BHARD], bh1 = ws[OFF_BHARD+1];
    const float* yF = ws + OFF_YF; const float* yB = ws + OFF_YB;
    #pragma unroll
    for (int t = 0; t < 15; t++){
      int rowb = (node*15 + t)*2;
      float y0 = yF[rowb]   + yB[rowb]   + bh0;
      float y1 = yF[rowb+1] + yB[rowb+1] + bh1;
      float2 u2 = *(const float2*)&gum[rowb];
      float g0 = -__logf(-__logf(u2.x + EPSG) + EPSG);
      float g1 = -__logf(-__logf(u2.y + EPSG) + EPSG);
      float w  = sigf(((y1+g1) - (y0+g0)) * (1.0f/TAU_));
      coeff[t] = sc[t]*rden*w;
    }
  }

  // P5: x accumulation into s_x (h values dead since P3 barrier)
  {
    float xa[16];
    #pragma unroll
    for (int il = 0; il < 16; il++) xa[il] = 0.f;
    #pragma unroll
    for (int t = 0; t < 15; t++){
      int jl = jbase | (t + (t >= i_b ? 1 : 0));
      float c = coeff[t];
      #pragma unroll
      for (int il = 0; il < 16; il++) xa[il] += c*s_v[(grp*16+il)*64 + jl];
    }
    __syncthreads();                      // all s_v reads done before alias write
    #pragma unroll
    for (int il = 0; il < 16; il++) s_x[nl*68 + grp*16 + il] = xa[il];
  }

  // P6: stage hidden_state into s_h0 (aliases dead s_k/s_v)
  for (int k = tid; k < 4096; k += 256)
    s_h0[(k>>6)*68 + (k&63)] = hid[base*64 + k];
  __syncthreads();

  // P7: final GRU cell, il-blocked by 4
  const float* wih = ws+OFF_WIHC; const float* whc = ws+OFF_WHHC;
  const float* bih = ws+OFF_BIHC; const float* bhc = ws+OFF_BHHC;
  for (int ilb = 0; ilb < 4; ilb++){
    float ac[24];
    #pragma unroll
    for (int q = 0; q < 4; q++){
      int l = grp*16 + ilb*4 + q;
      ac[q*6+0] = bih[l]; ac[q*6+1] = bih[64+l]; ac[q*6+2] = bih[128+l];
      ac[q*6+3] = bhc[l]; ac[q*6+4] = bhc[64+l]; ac[q*6+5] = bhc[128+l];
    }
    #pragma unroll
    for (int dq = 0; dq < 16; dq++){
      float4 x4 = *(const float4*)&s_x [nl*68 + 4*dq];
      float4 h4 = *(const float4*)&s_h0[nl*68 + 4*dq];
      #pragma unroll
      for (int q = 0; q < 4; q++){
        int l = grp*16 + ilb*4 + q;
        const float* w0 = wih + (l     )*64 + 4*dq;
        const float* w1 = wih + (64 + l)*64 + 4*dq;
        const float* w2 = wih + (128+ l)*64 + 4*dq;
        const float* m0 = whc + (l     )*64 + 4*dq;
        const float* m1 = whc + (64 + l)*64 + 4*dq;
        const float* m2 = whc + (128+ l)*64 + 4*dq;
        ac[q*6+0] += x4.x*w0[0]+x4.y*w0[1]+x4.z*w0[2]+x4.w*w0[3];
        ac[q*6+1] += x4.x*w1[0]+x4.y*w1[1]+x4.z*w1[2]+x4.w*w1[3];
        ac[q*6+2] += x4.x*w2[0]+x4.y*w2[1]+x4.z*w2[2]+x4.w*w2[3];
        ac[q*6+3] += h4.x*m0[0]+h4.y*m0[1]+h4.z*m0[2]+h4.w*m0[3];
        ac[q*6+4] += h4.x*m1[0]+h4.y*m1[1]+h4.z*m1[2]+h4.w*m1[3];
        ac[q*6+5] += h4.x*m2[0]+h4.y*m2[1]+h4.z*m2[2]+h4.w*m2[3];
      }
    }
    #pragma unroll
    for (int q = 0; q < 4; q++){
      int l = grp*16 + ilb*4 + q;
      float r = sigf(ac[q*6+0] + ac[q*6+3]);
      float z = sigf(ac[q*6+1] + ac[q*6+4]);
      float n = tanhfast(ac[q*6+2] + r*ac[q*6+5]);
      out[node*64 + l] = (1.0f - z)*n + z*s_h0[nl*68 + l];
    }
  }
}

extern "C" void kernel_launch(void* const* d_in, const int* in_sizes, int n_in,
                              void* d_out, int out_size, void* d_ws, size_t ws_size,
                              hipStream_t stream){
  if (ws_size < (size_t)WS_FLOATS * sizeof(float)) return;
  float* ws = (float*)d_ws;
  static const int offs[20] = {OFF_WENC, OFF_BENC, OFF_WIHF, OFF_WHHF, OFF_BIHF, OFF_BHHF,
      OFF_WIHB, OFF_WHHB, OFF_BIHB, OFF_BHHB, OFF_WHARD, OFF_BHARD, OFF_WQ, OFF_WK, OFF_WV,
      OFF_BV, OFF_WIHC, OFF_WHHC, OFF_BIHC, OFF_BHHC};
  Prep p;
  for (int i = 0; i < 20; i++){
    p.s[i] = (const float*)d_in[3 + i];
    p.n[i] = in_sizes[3 + i];
    p.o[i] = offs[i];
  }
  hipLaunchKernelGGL(k_prep, dim3(96, 20), dim3(256), 0, stream, p, ws);
  hipLaunchKernelGGL(k_gru,  dim3(512),    dim3(512), 0, stream,
                     (const float*)d_in[0], ws);
  hipLaunchKernelGGL(k_attn, dim3(256),    dim3(256), 0, stream,
                     (const float*)d_in[0], (const float*)d_in[1],
                     (const float*)d_in[2], ws, (float*)d_out);
}